// Round 1
// baseline (347.319 us; speedup 1.0000x reference)
//
#include <hip/hip_runtime.h>

#define NSTEPS 20
#define ALPHA  0.9f
#define VTH    1.0f
#define GSOMA  0.3f
#define ISCALE 0.5f

#define NOR  21
#define NORN 42
#define NLN  56
#define NPN  42
#define NKC  2000
#define NOD  34

#define TPB  256
#define KPER 8   // KCs per thread: 250 threads * 8 = 2000

__global__ __launch_bounds__(TPB)
void snn_kernel(const float* __restrict__ or_input,   // [B,21]
                const float* __restrict__ or_gains,   // [21]
                const float* __restrict__ mapping,    // [21,42]
                const float* __restrict__ orn_to_pn,  // [42,42]
                const float* __restrict__ orn_to_ln,  // [42,56]
                const float* __restrict__ ln_to_pn,   // [56,42]
                const float* __restrict__ pn_to_kc,   // [42,2000]
                const float* __restrict__ kc_to_apl,  // [2000,1]
                const float* __restrict__ apl_to_kc,  // [1,2000]
                const float* __restrict__ dec_w,      // [2000,34]
                const float* __restrict__ dec_b,      // [34]
                float* __restrict__ out)              // [B,34]
{
    __shared__ float sW_ol[NORN * NLN];   // orn_to_ln
    __shared__ float sW_op[NORN * NPN];   // orn_to_pn
    __shared__ float sW_lp[NLN * NPN];    // ln_to_pn
    __shared__ float sDrive[NORN];        // I_SCALE * orn_drive
    __shared__ float sSpg[NOR];
    __shared__ float sOrn[NORN];
    __shared__ float sLn[NLN];
    __shared__ float sApl;
    __shared__ float sRed[4];
    __shared__ float sRed2[4 * NOD];
    __shared__ unsigned long long sMask;  // PN spike bitmask

    const int tid = threadIdx.x;
    const int b   = blockIdx.x;

    // ---- stage weights into LDS ----
    for (int i = tid; i < NORN * NLN; i += TPB) sW_ol[i] = orn_to_ln[i];
    for (int i = tid; i < NORN * NPN; i += TPB) sW_op[i] = orn_to_pn[i];
    for (int i = tid; i < NLN * NPN;  i += TPB) sW_lp[i] = ln_to_pn[i];
    if (tid < NOR) sSpg[tid] = log1pf(expf(or_gains[tid]));  // softplus
    if (tid == 0)  sApl = 0.f;
    __syncthreads();

    // ---- orn_drive = (x * softplus(g)) @ mapping, pre-scaled by I_SCALE ----
    if (tid < NORN) {
        const float* x = or_input + (long)b * NOR;
        float d = 0.f;
        for (int i = 0; i < NOR; ++i) d += x[i] * sSpg[i] * mapping[i * NORN + tid];
        sDrive[tid] = d * ISCALE;
    }

    // ---- per-thread KC state (8 contiguous KCs) ----
    const int  kbase = tid * KPER;
    const bool act   = (kbase < NKC);   // tid < 250
    float vd[KPER], va[KPER], cnt[KPER], wa2k[KPER], wk2a[KPER];
#pragma unroll
    for (int j = 0; j < KPER; ++j) {
        vd[j] = 0.f; va[j] = 0.f; cnt[j] = 0.f;
        wa2k[j] = act ? apl_to_kc[kbase + j] : 0.f;
        wk2a[j] = act ? kc_to_apl[kbase + j] : 0.f;
    }
    float v_orn = 0.f, v_ln = 0.f, v_pn = 0.f, v_pn_exc = 0.f;
    __syncthreads();

    // ================= time loop =================
    for (int t = 0; t < NSTEPS; ++t) {
        // --- A: ORN LIF ---
        if (tid < NORN) {
            v_orn = ALPHA * v_orn + sDrive[tid];
            float s = (v_orn - VTH) > 0.f ? 1.f : 0.f;
            v_orn *= (1.f - s);
            sOrn[tid] = s;
        }
        __syncthreads();

        // --- B: LN (wave 0) + PN excitation (wave 1, in parallel) ---
        if (tid < NLN) {
            float a = 0.f;
            for (int o = 0; o < NORN; ++o) a += sOrn[o] * sW_ol[o * NLN + tid];
            v_ln = ALPHA * v_ln + a;
            float s = (v_ln - VTH) > 0.f ? 1.f : 0.f;
            v_ln *= (1.f - s);
            sLn[tid] = s;
        } else if (tid >= 64 && tid < 64 + NPN) {
            const int j = tid - 64;
            float a = 0.f;
            for (int o = 0; o < NORN; ++o) a += sOrn[o] * sW_op[o * NPN + j];
            v_pn_exc = a;
        }
        __syncthreads();

        // --- C: PN finish (wave 1), pack spikes into ballot mask ---
        if (tid >= 64 && tid < 64 + NPN) {
            const int j = tid - 64;
            float inh = 0.f;
            for (int l = 0; l < NLN; ++l) inh += sLn[l] * sW_lp[l * NPN + j];
            v_pn = ALPHA * v_pn + v_pn_exc - inh;
            bool s = (v_pn - VTH) > 0.f;
            if (s) v_pn = 0.f;
            unsigned long long bal = __ballot(s);   // bit j = PN j spike
            if (tid == 64) sMask = bal;
        }
        __syncthreads();

        // --- D: KC two-compartment + APL ---
        {
            const float apl = sApl;
#pragma unroll
            for (int j = 0; j < KPER; ++j) vd[j] = ALPHA * vd[j] - apl * wa2k[j];

            unsigned long long m = sMask;  // wave-uniform
            while (m) {
                const int p = __builtin_ctzll(m);
                m &= m - 1;
                if (act) {
                    const float4* w = (const float4*)(pn_to_kc + (long)p * NKC + kbase);
                    float4 w0 = w[0], w1 = w[1];
                    vd[0] += w0.x; vd[1] += w0.y; vd[2] += w0.z; vd[3] += w0.w;
                    vd[4] += w1.x; vd[5] += w1.y; vd[6] += w1.z; vd[7] += w1.w;
                }
            }

            float aplp = 0.f;
#pragma unroll
            for (int j = 0; j < KPER; ++j) {
                va[j] = ALPHA * va[j] + GSOMA * (vd[j] - va[j]);
                float s = (va[j] - VTH) > 0.f ? 1.f : 0.f;
                va[j] *= (1.f - s);
                cnt[j] += s;
                aplp += s * wk2a[j];
            }
            // block reduction of APL drive
            for (int off = 32; off > 0; off >>= 1) aplp += __shfl_xor(aplp, off, 64);
            if ((tid & 63) == 0) sRed[tid >> 6] = aplp;
        }
        __syncthreads();
        if (tid == 0) {
            float a = sRed[0] + sRed[1] + sRed[2] + sRed[3];
            sApl = fmaxf(a, 0.f);   // relu, APL_GAIN = 1
        }
    }

    // ================= epilogue: logits = (cnt/20) @ dec_w + dec_b =================
    float acc[NOD];
#pragma unroll
    for (int o = 0; o < NOD; ++o) acc[o] = 0.f;
    if (act) {
#pragma unroll
        for (int j = 0; j < KPER; ++j) {
            float r = cnt[j] / 20.0f;
            if (r != 0.f) {                       // KC sparsity: skip silent KCs
                const float* wr = dec_w + (long)(kbase + j) * NOD;
#pragma unroll
                for (int o = 0; o < NOD; ++o) acc[o] += r * wr[o];
            }
        }
    }
#pragma unroll
    for (int o = 0; o < NOD; ++o) {
        float v = acc[o];
        for (int off = 32; off > 0; off >>= 1) v += __shfl_xor(v, off, 64);
        if ((tid & 63) == 0) sRed2[(tid >> 6) * NOD + o] = v;
    }
    __syncthreads();
    if (tid < NOD) {
        float v = sRed2[tid] + sRed2[NOD + tid] + sRed2[2 * NOD + tid] +
                  sRed2[3 * NOD + tid] + dec_b[tid];
        out[(long)b * NOD + tid] = v;
    }
}

extern "C" void kernel_launch(void* const* d_in, const int* in_sizes, int n_in,
                              void* d_out, int out_size, void* d_ws, size_t ws_size,
                              hipStream_t stream) {
    (void)n_in; (void)out_size; (void)d_ws; (void)ws_size;
    const float* or_input  = (const float*)d_in[0];
    const float* or_gains  = (const float*)d_in[1];
    const float* mapping   = (const float*)d_in[2];
    const float* orn_to_pn = (const float*)d_in[3];
    const float* orn_to_ln = (const float*)d_in[4];
    const float* ln_to_pn  = (const float*)d_in[5];
    const float* pn_to_kc  = (const float*)d_in[6];
    const float* kc_to_apl = (const float*)d_in[7];
    const float* apl_to_kc = (const float*)d_in[8];
    const float* dec_w     = (const float*)d_in[9];
    const float* dec_b     = (const float*)d_in[10];
    float* out = (float*)d_out;

    const int batch = in_sizes[0] / NOR;  // 4096
    hipLaunchKernelGGL(snn_kernel, dim3(batch), dim3(TPB), 0, stream,
                       or_input, or_gains, mapping, orn_to_pn, orn_to_ln,
                       ln_to_pn, pn_to_kc, kc_to_apl, apl_to_kc, dec_w, dec_b, out);
}